// Round 2
// baseline (526.992 us; speedup 1.0000x reference)
//
#include <hip/hip_runtime.h>

// GaussianSmoothing3d: depthwise 3D conv, 3 ch, 5x5x5 separable Gaussian, SAME
// zero pad, fp32 (1,3,256,256,256).
//
// R3 restructure (was latency/barrier-bound at 143us/dispatch, VALU 30%,
// HBM 38%, occupancy 20%, 2.2e7 LDS-conflict cycles ~= 25% of kernel):
//  - NO LDS, NO barriers. Each wave owns a full x-row (64 lanes x float4).
//    Each thread walks z with a 5-deep register shift accumulator.
//  - x-halo: two aligned float2 loads (L1-hit, neighbors load same lines)
//    instead of cross-lane ops; edge lanes zeroed by select.
//  - y-halo: direct loads of rows y-2..y+2 (waves in block overlap 80% ->
//    L1/L2 absorb the 5x read amplification; HBM still fetches ~1x input).
//  - 1D weights recovered exactly from center fibers of the outer-product
//    kernel: kx[i] = w[2][2][i]/sum (15 uniform scalar loads, no barrier).
//  - Nontemporal output stores (native ext_vector_type for the builtin):
//    write-once stream must not evict cached input slices from L2/L3.
// Consecutive blocks = same z-window, adjacent y panels -> L2 locality.

#define N   256
#define ZC  32          // z-slices per block; 4-slice halo walk => 36 steps
#define NT  256

typedef float f4n __attribute__((ext_vector_type(4)));  // native vec for builtin

__global__ __launch_bounds__(NT) void gauss3d_kernel(
    const float* __restrict__ xin,
    const float* __restrict__ wxp,
    const float* __restrict__ wyp,
    const float* __restrict__ wzp,
    float* __restrict__ out)
{
    const int tid  = threadIdx.x;
    const int lane = tid & 63;
    const int wid  = __builtin_amdgcn_readfirstlane(tid >> 6);  // wave-uniform

    const int c  = blockIdx.z;                 // channel 0..2
    const int y  = blockIdx.x * 4 + wid;       // wave-uniform output row
    const int z0 = blockIdx.y * ZC;
    const int gx = lane << 2;                  // 4 output cols per thread

    const float* __restrict__ w = (c == 0) ? wxp : (c == 1) ? wyp : wzp;

    // --- 1D factors from the center fibers (exact for outer(k,k,k)/S) ---
    // layout [d][h][w]: x-fiber w[2][2][i]=60+i, y-fiber w[2][i][2]=52+5i,
    // z-fiber w[i][2][2]=25i+12; each normalized by its fiber sum.
    float kx[5], ky[5], kz[5];
    float sx = 0.f, sy = 0.f, sz = 0.f;
#pragma unroll
    for (int i = 0; i < 5; ++i) {
        kx[i] = w[60 + i];       sx += kx[i];
        ky[i] = w[52 + 5 * i];   sy += ky[i];
        kz[i] = w[25 * i + 12];  sz += kz[i];
    }
    const float rxs = 1.f / sx, rys = 1.f / sy, rzs = 1.f / sz;
#pragma unroll
    for (int i = 0; i < 5; ++i) { kx[i] *= rxs; ky[i] *= rys; kz[i] *= rzs; }

    const float* xc = xin + (size_t)c * N * N * N;
    float*       oc = out + (size_t)c * N * N * N;

    // --- per-row (y-halo) pointers; validity is wave-uniform and fixed ---
    bool rok[5];
    const float* rp[5];
#pragma unroll
    for (int h = 0; h < 5; ++h) {
        const int gy = y + h - 2;
        rok[h] = ((unsigned)gy < (unsigned)N);
        const int gyc = rok[h] ? gy : 0;
        rp[h] = xc + ((long)(z0 - 2) * N + gyc) * (long)N;  // deref'd only when valid
    }

    // --- x-edge handling: per-lane constant masks, always-in-bounds addrs ---
    const bool le = (gx == 0);
    const bool re = (gx == N - 4);
    const int  il = le ? 0  : gx - 2;   // 8B-aligned float2 at cols gx-2..gx-1
    const int  ir = re ? gx : gx + 4;   // 8B-aligned float2 at cols gx+4..gx+5

    float4 a0 = make_float4(0.f, 0.f, 0.f, 0.f);
    float4 a1 = a0, a2 = a0, a3 = a0, a4 = a0;

    float* op = oc + ((size_t)z0 * N + y) * N;  // output row base, += N*N per store

    for (int t = 0; t < ZC + 4; ++t) {
        const int  zs  = z0 - 2 + t;
        const bool zok = ((unsigned)zs < (unsigned)N);   // wave-uniform

        float4 yv = make_float4(0.f, 0.f, 0.f, 0.f);
#pragma unroll
        for (int h = 0; h < 5; ++h) {
            float4 v;  float2 lm, rm;
            if (zok && rok[h]) {                // uniform branch
                lm = *(const float2*)(rp[h] + il);
                v  = *(const float4*)(rp[h] + gx);
                rm = *(const float2*)(rp[h] + ir);
            } else {
                lm = make_float2(0.f, 0.f);
                v  = make_float4(0.f, 0.f, 0.f, 0.f);
                rm = make_float2(0.f, 0.f);
            }
            const float l0 = le ? 0.f : lm.x;
            const float l1 = le ? 0.f : lm.y;
            const float r0 = re ? 0.f : rm.x;
            const float r1 = re ? 0.f : rm.y;
            // x-conv for output cols gx..gx+3 (inputs gx-2..gx+5)
            const float o0 = kx[0]*l0  + kx[1]*l1  + kx[2]*v.x + kx[3]*v.y + kx[4]*v.z;
            const float o1 = kx[0]*l1  + kx[1]*v.x + kx[2]*v.y + kx[3]*v.z + kx[4]*v.w;
            const float o2 = kx[0]*v.x + kx[1]*v.y + kx[2]*v.z + kx[3]*v.w + kx[4]*r0;
            const float o3 = kx[0]*v.y + kx[1]*v.z + kx[2]*v.w + kx[3]*r0  + kx[4]*r1;
            const float kh = ky[h];
            yv.x += kh * o0; yv.y += kh * o1; yv.z += kh * o2; yv.w += kh * o3;
        }

#pragma unroll
        for (int h = 0; h < 5; ++h) rp[h] += N * N;

        // z accumulate: acc[j] (zo = zs-2+j) gets weight kz[4-j]
        a0.x += kz[4]*yv.x; a0.y += kz[4]*yv.y; a0.z += kz[4]*yv.z; a0.w += kz[4]*yv.w;
        a1.x += kz[3]*yv.x; a1.y += kz[3]*yv.y; a1.z += kz[3]*yv.z; a1.w += kz[3]*yv.w;
        a2.x += kz[2]*yv.x; a2.y += kz[2]*yv.y; a2.z += kz[2]*yv.z; a2.w += kz[2]*yv.w;
        a3.x += kz[1]*yv.x; a3.y += kz[1]*yv.y; a3.z += kz[1]*yv.z; a3.w += kz[1]*yv.w;
        a4.x += kz[0]*yv.x; a4.y += kz[0]*yv.y; a4.z += kz[0]*yv.z; a4.w += kz[0]*yv.w;

        if (t >= 4) {                           // plane zo = zs-2 complete
            f4n s;
            s.x = a0.x; s.y = a0.y; s.z = a0.z; s.w = a0.w;
            __builtin_nontemporal_store(s, (f4n*)(op + gx));
            op += N * N;
        }
        a0 = a1; a1 = a2; a2 = a3; a3 = a4;
        a4 = make_float4(0.f, 0.f, 0.f, 0.f);
    }
}

extern "C" void kernel_launch(void* const* d_in, const int* in_sizes, int n_in,
                              void* d_out, int out_size, void* d_ws, size_t ws_size,
                              hipStream_t stream) {
    const float* x  = (const float*)d_in[0];
    const float* wx = (const float*)d_in[1];
    const float* wy = (const float*)d_in[2];
    const float* wz = (const float*)d_in[3];
    float* o = (float*)d_out;

    dim3 grid(N / 4, N / ZC, 3);   // 64 y-panels x 8 z-chunks x 3 ch = 1536 blocks
    dim3 block(NT);
    gauss3d_kernel<<<grid, block, 0, stream>>>(x, wx, wy, wz, o);
}

// Round 3
// 472.419 us; speedup vs baseline: 1.1155x; 1.1155x over previous
//
#include <hip/hip_runtime.h>

// GaussianSmoothing3d: depthwise 3D conv, 3 ch, 5x5x5 separable Gaussian, SAME
// zero pad, fp32 (1,3,256,256,256).
//
// R4: R3's no-LDS register z-walk was latency-bound (300us, HBM 1.4TB/s,
// VALU 30%): every z-step was a serial 15-load -> vmcnt(0) -> compute chain.
// Changes:
//  - Software pipeline: double register buffer vA/vB, loads for slice t+1
//    issued BEFORE computing slice t -> compiler waits at vmcnt(5), L2
//    latency hides under the ~350cy of FMAs per step.
//  - x-halo via ds_bpermute from neighbor lanes (4/row, conflict-free,
//    LDS pipe overlaps VALU) instead of 10 extra float2 loads: 15 -> 5
//    vmem ops per step, way less address VALU.
//  - Edge lanes (0,63) get wrong wrapped data from bpermute; zeroed by the
//    same le/re selects that implement the zero padding.
//  - Row base pointers are wave-uniform (SGPR) -> loads are s-base + gx.
//  - Nontemporal float4 output stores.

#define N   256
#define ZC  32          // z-slices per block; 4-halo walk => 36 steps
#define NT  256
#define NN  (N * N)

typedef float f4n __attribute__((ext_vector_type(4)));

__global__ __launch_bounds__(NT) void gauss3d_kernel(
    const float* __restrict__ xin,
    const float* __restrict__ wxp,
    const float* __restrict__ wyp,
    const float* __restrict__ wzp,
    float* __restrict__ out)
{
    const int tid  = threadIdx.x;
    const int lane = tid & 63;
    const int wid  = __builtin_amdgcn_readfirstlane(tid >> 6);  // wave-uniform

    const int c  = blockIdx.z;                 // channel 0..2
    const int y  = blockIdx.x * 4 + wid;       // wave-uniform output row
    const int z0 = blockIdx.y * ZC;
    const int gx = lane << 2;                  // 4 output cols per thread

    const float* __restrict__ w = (c == 0) ? wxp : (c == 1) ? wyp : wzp;

    // 1D factors from center fibers of outer(k,k,k)/S (exact).
    // layout [d][h][w]: x-fiber w[2][2][i]=60+i, y w[2][i][2]=52+5i,
    // z w[i][2][2]=25i+12; normalize each by its fiber sum.
    float kx[5], ky[5], kz[5];
    float sx = 0.f, sy = 0.f, sz = 0.f;
#pragma unroll
    for (int i = 0; i < 5; ++i) {
        kx[i] = w[60 + i];       sx += kx[i];
        ky[i] = w[52 + 5 * i];   sy += ky[i];
        kz[i] = w[25 * i + 12];  sz += kz[i];
    }
    const float rxs = 1.f / sx, rys = 1.f / sy, rzs = 1.f / sz;
#pragma unroll
    for (int i = 0; i < 5; ++i) { kx[i] *= rxs; ky[i] *= rys; kz[i] *= rzs; }

    const float* xc = xin + (size_t)c * N * NN;
    float*       oc = out + (size_t)c * N * NN;

    // per-row (y-halo) bases; wave-uniform, advance one slice per LOAD
    bool rok[5];
    const float* rp[5];
#pragma unroll
    for (int h = 0; h < 5; ++h) {
        const int gy = y + h - 2;
        rok[h] = ((unsigned)gy < (unsigned)N);
        rp[h] = xc + ((long)(z0 - 2) * N + (rok[h] ? gy : 0)) * (long)N;
    }

    // x-edge masks + bpermute lane addresses (bytes)
    const bool le = (lane == 0);
    const bool re = (lane == 63);
    const int upA = ((lane + 63) & 63) << 2;   // lane-1 (wraps; masked by le)
    const int dnA = ((lane + 1) & 63) << 2;    // lane+1 (wraps; masked by re)

    float4 a0 = make_float4(0.f, 0.f, 0.f, 0.f);
    float4 a1 = a0, a2 = a0, a3 = a0, a4 = a0;

    float* op = oc + ((size_t)z0 * N + y) * N + gx;

    float4 vA[5], vB[5];

    auto LOADS = [&](float4 vv[5], int tt) {
        const int  zs  = z0 - 2 + tt;
        const bool zok = (tt < ZC + 4) && ((unsigned)zs < (unsigned)N); // uniform
#pragma unroll
        for (int h = 0; h < 5; ++h) {
            if (zok && rok[h]) vv[h] = *(const float4*)(rp[h] + gx);
            else               vv[h] = make_float4(0.f, 0.f, 0.f, 0.f);
            rp[h] += NN;
        }
    };

    auto COMPUTE = [&](const float4 vv[5], int t) {
        float4 yv = make_float4(0.f, 0.f, 0.f, 0.f);
#pragma unroll
        for (int h = 0; h < 5; ++h) {
            const float4 v = vv[h];
            float l0 = __int_as_float(__builtin_amdgcn_ds_bpermute(upA, __float_as_int(v.z)));
            float l1 = __int_as_float(__builtin_amdgcn_ds_bpermute(upA, __float_as_int(v.w)));
            float r0 = __int_as_float(__builtin_amdgcn_ds_bpermute(dnA, __float_as_int(v.x)));
            float r1 = __int_as_float(__builtin_amdgcn_ds_bpermute(dnA, __float_as_int(v.y)));
            l0 = le ? 0.f : l0;  l1 = le ? 0.f : l1;
            r0 = re ? 0.f : r0;  r1 = re ? 0.f : r1;
            // x-conv for output cols gx..gx+3 (inputs gx-2..gx+5)
            const float o0 = kx[0]*l0  + kx[1]*l1  + kx[2]*v.x + kx[3]*v.y + kx[4]*v.z;
            const float o1 = kx[0]*l1  + kx[1]*v.x + kx[2]*v.y + kx[3]*v.z + kx[4]*v.w;
            const float o2 = kx[0]*v.x + kx[1]*v.y + kx[2]*v.z + kx[3]*v.w + kx[4]*r0;
            const float o3 = kx[0]*v.y + kx[1]*v.z + kx[2]*v.w + kx[3]*r0  + kx[4]*r1;
            const float kh = ky[h];
            yv.x += kh * o0; yv.y += kh * o1; yv.z += kh * o2; yv.w += kh * o3;
        }
        // z accumulate: acc[j] (zo = zs-2+j) gets weight kz[4-j]
        a0.x += kz[4]*yv.x; a0.y += kz[4]*yv.y; a0.z += kz[4]*yv.z; a0.w += kz[4]*yv.w;
        a1.x += kz[3]*yv.x; a1.y += kz[3]*yv.y; a1.z += kz[3]*yv.z; a1.w += kz[3]*yv.w;
        a2.x += kz[2]*yv.x; a2.y += kz[2]*yv.y; a2.z += kz[2]*yv.z; a2.w += kz[2]*yv.w;
        a3.x += kz[1]*yv.x; a3.y += kz[1]*yv.y; a3.z += kz[1]*yv.z; a3.w += kz[1]*yv.w;
        a4.x += kz[0]*yv.x; a4.y += kz[0]*yv.y; a4.z += kz[0]*yv.z; a4.w += kz[0]*yv.w;

        if (t >= 4) {                           // plane zo = zs-2 complete
            f4n s;
            s.x = a0.x; s.y = a0.y; s.z = a0.z; s.w = a0.w;
            __builtin_nontemporal_store(s, (f4n*)op);
            op += NN;
        }
        a0 = a1; a1 = a2; a2 = a3; a3 = a4;
        a4 = make_float4(0.f, 0.f, 0.f, 0.f);
    };

    // software pipeline: loads for step t+1 in flight while computing step t
    LOADS(vA, 0);
    for (int t = 0; t < ZC + 4; t += 2) {
        LOADS(vB, t + 1);
        COMPUTE(vA, t);
        LOADS(vA, t + 2);      // t+2==36 on last iter -> zok false, zero-fill
        COMPUTE(vB, t + 1);
    }
}

extern "C" void kernel_launch(void* const* d_in, const int* in_sizes, int n_in,
                              void* d_out, int out_size, void* d_ws, size_t ws_size,
                              hipStream_t stream) {
    const float* x  = (const float*)d_in[0];
    const float* wx = (const float*)d_in[1];
    const float* wy = (const float*)d_in[2];
    const float* wz = (const float*)d_in[3];
    float* o = (float*)d_out;

    dim3 grid(N / 4, N / ZC, 3);   // 64 y-panels x 8 z-chunks x 3 ch = 1536 blocks
    dim3 block(NT);
    gauss3d_kernel<<<grid, block, 0, stream>>>(x, wx, wy, wz, o);
}

// Round 4
// 368.198 us; speedup vs baseline: 1.4313x; 1.2831x over previous
//
#include <hip/hip_runtime.h>

// GaussianSmoothing3d: depthwise 3D conv, 3 ch, 5x5x5 separable Gaussian, SAME
// zero pad, fp32 (1,3,256,256,256).
//
// R5: back to R2's LDS-staging structure (it reached 3.07 TB/s; the no-LDS
// variants R3/R4 were cache-latency-bound at 1.4-1.7 TB/s), fixing R2's two
// measured losses:
//  - DOUBLE-BUFFERED LDS, 1 barrier/round (was 2): COMPUTE(buf[r&1]) while
//    the global loads for round r+1 (issued at end of round r-1) are in
//    flight; ds_write to buf[(r+1)&1] happens after compute, by which time
//    the loads have landed -> vmcnt wait ~free, barrier no longer drains
//    outstanding HBM latency.
//  - Weight 1D factors from center fibers in registers (exact, verified
//    R3/R4) -> no k1 LDS pass, no extra barrier.
//  - LROW 72 (row offset = 8 banks, was 4) vs R2's 68; nontemporal stores.
// Staging: 11 independent float2 loads/thread/round (deep MLP, each HBM
// byte read ~1.06x); compute: 2 aligned ds_read_b128 per row, x/y-conv in
// registers, 5-deep z register shift accumulator.

#define N     256
#define NN    (N * N)
#define TX    64
#define TY    16
#define TZ    32
#define ZB    4
#define NT    256
#define LROW  72                       // floats per staged row slot (pos p = col p-2; 68 used)
#define ROWS  (TY + 4)                 // 20
#define UPR   34                       // float2 units per row
#define UNITS (ZB * ROWS * UPR)        // 2720
#define MAXU  ((UNITS + NT - 1) / NT)  // 11
#define NRND  ((TZ + 4) / ZB)          // 9

typedef float f4n __attribute__((ext_vector_type(4)));

__global__ __launch_bounds__(NT) void gauss3d_kernel(
    const float* __restrict__ xin,
    const float* __restrict__ wxp,
    const float* __restrict__ wyp,
    const float* __restrict__ wzp,
    float* __restrict__ out)
{
    __shared__ float raw[2][ZB][ROWS][LROW];   // 2 x 23040 B = 46080 B

    const int tid = threadIdx.x;
    const int c   = blockIdx.z / (N / TZ);
    const int zt  = blockIdx.z % (N / TZ);
    const int x0  = blockIdx.x * TX;
    const int y0  = blockIdx.y * TY;
    const int z0  = zt * TZ;

    const float* __restrict__ w = (c == 0) ? wxp : (c == 1) ? wyp : wzp;

    // 1D factors from center fibers of outer(k,k,k)/S (exact; see R3).
    // layout [d][h][w]: x-fiber w[2][2][i]=60+i, y w[2][i][2]=52+5i,
    // z w[i][2][2]=25i+12; normalize each by its fiber sum.
    float kx[5], ky[5], kz[5];
    float sx = 0.f, sy = 0.f, sz = 0.f;
#pragma unroll
    for (int i = 0; i < 5; ++i) {
        kx[i] = w[60 + i];       sx += kx[i];
        ky[i] = w[52 + 5 * i];   sy += ky[i];
        kz[i] = w[25 * i + 12];  sz += kz[i];
    }
    const float rxs = 1.f / sx, rys = 1.f / sy, rzs = 1.f / sz;
#pragma unroll
    for (int i = 0; i < 5; ++i) { kx[i] *= rxs; ky[i] *= rys; kz[i] *= rzs; }

    const float* xc = xin + (size_t)c * N * NN;
    float*       oc = out + (size_t)c * N * NN;

    const int iy = tid >> 4;          // 0..15
    const int ix = (tid & 15) << 2;   // 0,4,...,60

    float4 a0 = make_float4(0.f, 0.f, 0.f, 0.f);
    float4 a1 = a0, a2 = a0, a3 = a0, a4 = a0;

    // ---- staging: issue loads (deep MLP) ----
    float2 v[MAXU];
    auto LOADP = [&](int rnd) {
        const int  zb  = z0 - 2 + rnd * ZB;
        const bool rv  = (rnd < NRND);           // uniform
#pragma unroll
        for (int i = 0; i < MAXU; ++i) {
            v[i] = make_float2(0.f, 0.f);
            const int u = tid + i * NT;
            if (u < UNITS) {
                const int rowi = u / UPR;            // 0..79
                const int j    = u - rowi * UPR;     // 0..33
                const int s    = rowi / ROWS;        // 0..3
                const int r    = rowi - s * ROWS;    // 0..19
                const int zs  = zb + s;
                const int gy  = y0 + r - 2;
                const int gxl = x0 - 2 + 2 * j;      // even; pair never straddles 0/256
                if (rv && (unsigned)zs < (unsigned)N && (unsigned)gy < (unsigned)N &&
                    (unsigned)gxl < (unsigned)N)
                    v[i] = *(const float2*)&xc[((size_t)zs * N + gy) * N + gxl];
            }
        }
    };
    // ---- staging: LDS writes (unit u -> float offset 2u + 4*rowi) ----
    auto WRITEP = [&](int bsel) {
        float* rawf = &raw[bsel][0][0][0];
#pragma unroll
        for (int i = 0; i < MAXU; ++i) {
            const int u = tid + i * NT;
            if (u < UNITS) {
                const int rowi = u / UPR;
                *(float2*)&rawf[2 * u + 4 * rowi] = v[i];   // rowi*LROW + 2j
            }
        }
    };

    auto COMPUTE = [&](int bsel, int rnd) {
        const int zb = z0 - 2 + rnd * ZB;
#pragma unroll
        for (int s = 0; s < ZB; ++s) {
            float4 yv = make_float4(0.f, 0.f, 0.f, 0.f);
#pragma unroll
            for (int h = 0; h < 5; ++h) {
                const float* rp = &raw[bsel][s][iy + h][ix];   // 16B aligned
                const float4 a = *(const float4*)rp;
                const float4 b = *(const float4*)(rp + 4);
                // x-conv: pos ix..ix+7 hold input cols ix-2..ix+5
                const float o0 = kx[0]*a.x + kx[1]*a.y + kx[2]*a.z + kx[3]*a.w + kx[4]*b.x;
                const float o1 = kx[0]*a.y + kx[1]*a.z + kx[2]*a.w + kx[3]*b.x + kx[4]*b.y;
                const float o2 = kx[0]*a.z + kx[1]*a.w + kx[2]*b.x + kx[3]*b.y + kx[4]*b.z;
                const float o3 = kx[0]*a.w + kx[1]*b.x + kx[2]*b.y + kx[3]*b.z + kx[4]*b.w;
                const float kh = ky[h];
                yv.x += kh * o0; yv.y += kh * o1; yv.z += kh * o2; yv.w += kh * o3;
            }
            // z accumulate: acc[j] (zo = zs-2+j) gets weight kz[4-j]
            a0.x += kz[4]*yv.x; a0.y += kz[4]*yv.y; a0.z += kz[4]*yv.z; a0.w += kz[4]*yv.w;
            a1.x += kz[3]*yv.x; a1.y += kz[3]*yv.y; a1.z += kz[3]*yv.z; a1.w += kz[3]*yv.w;
            a2.x += kz[2]*yv.x; a2.y += kz[2]*yv.y; a2.z += kz[2]*yv.z; a2.w += kz[2]*yv.w;
            a3.x += kz[1]*yv.x; a3.y += kz[1]*yv.y; a3.z += kz[1]*yv.z; a3.w += kz[1]*yv.w;
            a4.x += kz[0]*yv.x; a4.y += kz[0]*yv.y; a4.z += kz[0]*yv.z; a4.w += kz[0]*yv.w;

            const int zo = zb + s - 2;            // plane complete after this slice
            if (zo >= z0) {
                f4n st;
                st.x = a0.x; st.y = a0.y; st.z = a0.z; st.w = a0.w;
                __builtin_nontemporal_store(st,
                    (f4n*)&oc[((size_t)zo * N + (y0 + iy)) * N + (x0 + ix)]);
            }
            a0 = a1; a1 = a2; a2 = a3; a3 = a4;
            a4 = make_float4(0.f, 0.f, 0.f, 0.f);
        }
    };

    // ---- pipeline: loads for round r+1 fly under COMPUTE(round r) ----
    LOADP(0);
    WRITEP(0);          // one-time exposed vmcnt wait
    LOADP(1);
    __syncthreads();    // buf0 ready

    for (int rnd = 0; rnd < NRND; ++rnd) {
        COMPUTE(rnd & 1, rnd);
        if (rnd < NRND - 1) {
            WRITEP((rnd + 1) & 1);   // waits on loads issued last round (landed)
            LOADP(rnd + 2);          // in flight during next round's compute
            __syncthreads();         // buf[(rnd+1)&1] ready; readers of it done long ago
        }
    }
}

extern "C" void kernel_launch(void* const* d_in, const int* in_sizes, int n_in,
                              void* d_out, int out_size, void* d_ws, size_t ws_size,
                              hipStream_t stream) {
    const float* x  = (const float*)d_in[0];
    const float* wx = (const float*)d_in[1];
    const float* wy = (const float*)d_in[2];
    const float* wz = (const float*)d_in[3];
    float* o = (float*)d_out;

    dim3 grid(N / TX, N / TY, 3 * (N / TZ));   // 4 x 16 x 24 = 1536 blocks
    dim3 block(NT);
    gauss3d_kernel<<<grid, block, 0, stream>>>(x, wx, wy, wz, o);
}